// Round 6
// baseline (303.040 us; speedup 1.0000x reference)
//
#include <hip/hip_runtime.h>
#include <hip/hip_bf16.h>

#define LOOKBACK 96
#define HID 128
#define HORIZON 24
#define NLAYERS 3

typedef __attribute__((ext_vector_type(8))) short short8v;
typedef __attribute__((ext_vector_type(4))) float f32x4;

__device__ __forceinline__ float bf_lo(uint u) { return __uint_as_float(u << 16); }
__device__ __forceinline__ float bf_hi(uint u) { return __uint_as_float(u & 0xffff0000u); }
__device__ __forceinline__ ushort f2bf(float f) {
    __hip_bfloat16 h = __float2bfloat16(f);
    return *(ushort*)&h;
}

// ---------------------------------------------------------------------------
// weight prep: transpose + cast all weights to bf16 W^T, once per call
//   WinT [128][96], WsT [3][128][128], WoutT [32][128] (rows 24..31 zero)
// total indices: 12288 + 49152 + 3072 + 1024 = 65536 -> 256 blocks
// ---------------------------------------------------------------------------
__global__ void wprep_k(const float* __restrict__ W_in, const float* __restrict__ Ws,
                        const float* __restrict__ W_out,
                        ushort* __restrict__ WinT, ushort* __restrict__ WsT,
                        ushort* __restrict__ WoutT) {
    int idx = blockIdx.x * 256 + threadIdx.x;
    if (idx < 12288) {                       // W_in [96][128]
        int k = idx / 128, c = idx % 128;
        WinT[c * 96 + k] = f2bf(W_in[idx]);
    } else if (idx < 61440) {                // Ws [3][128][128]
        int r = idx - 12288;
        int l = r / 16384, q = r % 16384;
        int k = q / 128, c = q % 128;
        WsT[l * 16384 + c * 128 + k] = f2bf(Ws[r]);
    } else if (idx < 64512) {                // W_out [128][24]
        int r = idx - 61440;
        int k = r / 24, c = r % 24;
        WoutT[c * 128 + k] = f2bf(W_out[r]);
    } else {                                 // pad rows 24..31 of WoutT
        int r = idx - 64512;
        WoutT[24 * 128 + r] = 0;
    }
}

// ---------------------------------------------------------------------------
// CSR build
// ---------------------------------------------------------------------------
__global__ void zero_counts_k(int* __restrict__ counts, int n) {
    int i = blockIdx.x * blockDim.x + threadIdx.x;
    if (i < n) counts[i] = 0;
}

__global__ void hist_k(const int* __restrict__ dst, int* __restrict__ counts, int E) {
    int e = blockIdx.x * blockDim.x + threadIdx.x;
    if (e < E) atomicAdd(&counts[dst[e]], 1);
}

__global__ __launch_bounds__(1024) void bsum_k(const int* __restrict__ counts,
                                               int* __restrict__ bsum, int n) {
    __shared__ int s[1024];
    int t = threadIdx.x;
    int i = blockIdx.x * 1024 + t;
    s[t] = (i < n) ? counts[i] : 0;
    __syncthreads();
    for (int off = 512; off > 0; off >>= 1) {
        if (t < off) s[t] += s[t + off];
        __syncthreads();
    }
    if (t == 0) bsum[blockIdx.x] = s[0];
}

__global__ __launch_bounds__(1024) void scan_bsum_k(int* __restrict__ bsum, int nb) {
    __shared__ int s[1024];
    int t = threadIdx.x;
    int orig = (t < nb) ? bsum[t] : 0;
    s[t] = orig;
    __syncthreads();
    for (int off = 1; off < 1024; off <<= 1) {
        int x = s[t];
        int y = (t >= off) ? s[t - off] : 0;
        __syncthreads();
        s[t] = x + y;
        __syncthreads();
    }
    if (t < nb) bsum[t] = s[t] - orig;   // exclusive
}

// local scan + block offset -> offsets, cursor; also dinv = rsqrt(count+1)
__global__ __launch_bounds__(1024) void scan_local_k(const int* __restrict__ counts,
                                                     const int* __restrict__ bsum,
                                                     int* __restrict__ offsets,
                                                     int* __restrict__ cursor,
                                                     float* __restrict__ dinv, int n) {
    __shared__ int s[1024];
    int t = threadIdx.x;
    int i = blockIdx.x * 1024 + t;
    int c = (i < n) ? counts[i] : 0;
    s[t] = c;
    __syncthreads();
    for (int off = 1; off < 1024; off <<= 1) {
        int x = s[t];
        int y = (t >= off) ? s[t - off] : 0;
        __syncthreads();
        s[t] = x + y;
        __syncthreads();
    }
    if (i < n) {
        int o = bsum[blockIdx.x] + s[t] - c;
        offsets[i] = o;
        cursor[i] = o;
        dinv[i] = rsqrtf((float)c + 1.0f);
    }
}

__global__ void scatter_k(const int* __restrict__ src, const int* __restrict__ dst,
                          int* __restrict__ cursor, int* __restrict__ srcs, int E) {
    int e = blockIdx.x * blockDim.x + threadIdx.x;
    if (e >= E) return;
    int pos = atomicAdd(&cursor[dst[e]], 1);
    srcs[pos] = src[e];
}

// ---------------------------------------------------------------------------
// fused aggregation, feature-split: pass handles 64 features [CBASE, CBASE+64)
// lanes 0..31: even edges, lanes 32..63: odd edges; shfl_xor(32) combine
// out[i][c] = relu( dinv[i]*( zh[i][c] + Sum_e zh[src][c] ) + bias[c] )
// ---------------------------------------------------------------------------
template <int CBASE>
__global__ __launch_bounds__(256) void agg_k(
    const ushort* __restrict__ zh, ushort* __restrict__ out,
    const float* __restrict__ dinv,
    const int* __restrict__ offsets, const int* __restrict__ counts,
    const int* __restrict__ srcs,
    const float* __restrict__ bias, int n)
{
    int node = (blockIdx.x * 256 + threadIdx.x) >> 6;
    if (node >= n) return;
    node = __builtin_amdgcn_readfirstlane(node);   // wave-uniform -> scalar loads
    int lane = threadIdx.x & 63;
    int half = lane >> 5;
    int c = CBASE + (lane & 31) * 2;

    float di = dinv[node];
    uint sv = *(const uint*)&zh[(size_t)node * HID + c];
    float s0 = half ? 0.0f : bf_lo(sv);
    float s1 = half ? 0.0f : bf_hi(sv);

    int cnt = counts[node];
    const int* ep = srcs + offsets[node];
    int pairs = cnt >> 1;
    #pragma unroll 4
    for (int p = 0; p < pairs; ++p) {
        int sA = ep[2 * p];
        int sB = ep[2 * p + 1];
        int s = half ? sB : sA;
        uint u = *(const uint*)&zh[(size_t)s * HID + c];
        s0 += bf_lo(u);
        s1 += bf_hi(u);
    }
    if ((cnt & 1) && half == 0) {
        int s = ep[cnt - 1];
        uint u = *(const uint*)&zh[(size_t)s * HID + c];
        s0 += bf_lo(u);
        s1 += bf_hi(u);
    }

    s0 += __shfl_xor(s0, 32);
    s1 += __shfl_xor(s1, 32);

    if (half == 0) {
        float2 bv = *(const float2*)&bias[c];
        float r0 = fmaxf(fmaf(di, s0, bv.x), 0.0f);
        float r1 = fmaxf(fmaf(di, s1, bv.y), 0.0f);
        uint pk = (uint)f2bf(r0) | ((uint)f2bf(r1) << 16);
        *(uint*)&out[(size_t)node * HID + c] = pk;
    }
}

// ---------------------------------------------------------------------------
// MFMA GEMM (no LDS): C_bf16[n][128] = op( A[n][K] @ BT^T )
//   BT: bf16 [128][K]  (B transposed, row = output col)
//   AF32: A is f32; BIAS: +bias[col]; SCALE: *dinv[row]
// 256 threads = 4 waves; tile 64 rows x 128 cols; 16 rows/wave
// ---------------------------------------------------------------------------
template <int K, bool AF32, bool BIAS, bool SCALE>
__global__ __launch_bounds__(256) void mfma_gemm_k(
    const void* __restrict__ Araw, const ushort* __restrict__ BT,
    const float* __restrict__ bias, const float* __restrict__ dinv,
    ushort* __restrict__ C, int n)
{
    const int tid = threadIdx.x;
    const int wid = tid >> 6;
    const int lane = tid & 63;
    const int brow = blockIdx.x * 64;
    const int arow = brow + wid * 16 + (lane & 15);
    const int rowc = (arow < n) ? arow : (n - 1);
    const int kb = (lane >> 4) * 8;

    f32x4 acc[8];
    #pragma unroll
    for (int j = 0; j < 8; ++j) acc[j] = (f32x4){0.f, 0.f, 0.f, 0.f};

    #pragma unroll
    for (int kt = 0; kt < K / 32; ++kt) {
        short8v a;
        if (AF32) {
            const float* ap = (const float*)Araw + (size_t)rowc * K + kt * 32 + kb;
            float4 f0 = *(const float4*)ap;
            float4 f1 = *(const float4*)(ap + 4);
            a[0] = (short)f2bf(f0.x); a[1] = (short)f2bf(f0.y);
            a[2] = (short)f2bf(f0.z); a[3] = (short)f2bf(f0.w);
            a[4] = (short)f2bf(f1.x); a[5] = (short)f2bf(f1.y);
            a[6] = (short)f2bf(f1.z); a[7] = (short)f2bf(f1.w);
        } else {
            a = *(const short8v*)((const ushort*)Araw + (size_t)rowc * K + kt * 32 + kb);
        }
        #pragma unroll
        for (int j = 0; j < 8; ++j) {
            short8v b = *(const short8v*)&BT[(size_t)(j * 16 + (lane & 15)) * K + kt * 32 + kb];
            acc[j] = __builtin_amdgcn_mfma_f32_16x16x32_bf16(a, b, acc[j], 0, 0, 0);
        }
    }

    // epilogue: col = lane&15 (+16j), row = (lane>>4)*4 + r
    const int r0 = brow + wid * 16 + (lane >> 4) * 4;
    const int cl = lane & 15;
    float dsc[4];
    if (SCALE) {
        #pragma unroll
        for (int r = 0; r < 4; ++r) dsc[r] = (r0 + r < n) ? dinv[r0 + r] : 0.0f;
    }
    #pragma unroll
    for (int j = 0; j < 8; ++j) {
        int col = j * 16 + cl;
        float bv = BIAS ? bias[col] : 0.0f;
        #pragma unroll
        for (int r = 0; r < 4; ++r) {
            int row = r0 + r;
            if (row < n) {
                float v = acc[j][r];
                if (SCALE) v *= dsc[r];
                if (BIAS) v += bv;
                C[(size_t)row * HID + col] = f2bf(v);
            }
        }
    }
}

// ---------------------------------------------------------------------------
// output MFMA GEMM: out_f32[n][24] = A_bf16[n][128] @ WoutT^T + b ; fuses y copy
// WoutT bf16 [32][128] (rows 24..31 zero). tile 64 rows x 32 cols.
// ---------------------------------------------------------------------------
__global__ __launch_bounds__(256) void gemm_out_k(
    const ushort* __restrict__ A, const ushort* __restrict__ BT,
    const float* __restrict__ bias, const float* __restrict__ y,
    float* __restrict__ out, float* __restrict__ ycopy, int n)
{
    const int tid = threadIdx.x;
    const int wid = tid >> 6;
    const int lane = tid & 63;
    const int brow = blockIdx.x * 64;
    const int arow = brow + wid * 16 + (lane & 15);
    const int rowc = (arow < n) ? arow : (n - 1);
    const int kb = (lane >> 4) * 8;

    f32x4 acc[2];
    acc[0] = (f32x4){0.f, 0.f, 0.f, 0.f};
    acc[1] = (f32x4){0.f, 0.f, 0.f, 0.f};

    #pragma unroll
    for (int kt = 0; kt < 4; ++kt) {
        short8v a = *(const short8v*)(A + (size_t)rowc * HID + kt * 32 + kb);
        #pragma unroll
        for (int j = 0; j < 2; ++j) {
            short8v b = *(const short8v*)&BT[(size_t)(j * 16 + (lane & 15)) * HID + kt * 32 + kb];
            acc[j] = __builtin_amdgcn_mfma_f32_16x16x32_bf16(a, b, acc[j], 0, 0, 0);
        }
    }

    const int r0 = brow + wid * 16 + (lane >> 4) * 4;
    const int cl = lane & 15;
    #pragma unroll
    for (int j = 0; j < 2; ++j) {
        int col = j * 16 + cl;
        if (col < HORIZON) {
            float bv = bias[col];
            #pragma unroll
            for (int r = 0; r < 4; ++r) {
                int row = r0 + r;
                if (row < n) out[(size_t)row * HORIZON + col] = acc[j][r] + bv;
            }
        }
    }

    // fused y copy: this block's 64 rows = 384 float4s
    const float4* y4 = (const float4*)y;
    float4* o4 = (float4*)ycopy;
    const int lim = n * 6;          // n*24/4
    int base = blockIdx.x * 384;
    for (int t = tid; t < 384; t += 256) {
        int i = base + t;
        if (i < lim) o4[i] = y4[i];
    }
}

// ---------------------------------------------------------------------------
extern "C" void kernel_launch(void* const* d_in, const int* in_sizes, int n_in,
                              void* d_out, int out_size, void* d_ws, size_t ws_size,
                              hipStream_t stream) {
    const float* x     = (const float*)d_in[0];
    const float* y     = (const float*)d_in[1];
    const int*   ei    = (const int*)d_in[2];     // int64 in ref -> int32 on device
    const float* W_in  = (const float*)d_in[3];
    const float* b_in  = (const float*)d_in[4];
    const float* Ws    = (const float*)d_in[5];
    const float* bs    = (const float*)d_in[6];
    const float* W_out = (const float*)d_in[7];
    const float* b_out = (const float*)d_in[8];
    float* out = (float*)d_out;

    const int n = in_sizes[0] / LOOKBACK;
    const int E = in_sizes[2] / 2;
    const int* src = ei;
    const int* dst = ei + E;
    const int nb = (n + 1023) / 1024;

    // workspace layout (all 16B-aligned for n=50000, E=600000)
    char* p = (char*)d_ws;
    float*  dinv    = (float*)p;   p += (size_t)n * 4;
    int*    counts  = (int*)p;     p += (size_t)n * 4;
    int*    offsets = (int*)p;     p += (size_t)n * 4;
    int*    cursor  = (int*)p;     p += (size_t)n * 4;
    int*    bsum    = (int*)p;     p += (size_t)1024 * 4;
    int*    srcs    = (int*)p;     p += (size_t)E * 4;
    ushort* WinT    = (ushort*)p;  p += (size_t)128 * 96 * 2;
    ushort* WsT     = (ushort*)p;  p += (size_t)NLAYERS * 128 * 128 * 2;
    ushort* WoutT   = (ushort*)p;  p += (size_t)32 * 128 * 2;
    ushort* bufA    = (ushort*)p;  p += (size_t)n * HID * 2;
    ushort* bufB    = (ushort*)p;

    const int B = 256;
    // ---- weight prep + CSR build ----
    wprep_k<<<256, 256, 0, stream>>>(W_in, Ws, W_out, WinT, WsT, WoutT);
    zero_counts_k<<<(n + B - 1) / B, B, 0, stream>>>(counts, n);
    hist_k<<<(E + B - 1) / B, B, 0, stream>>>(dst, counts, E);
    bsum_k<<<nb, 1024, 0, stream>>>(counts, bsum, n);
    scan_bsum_k<<<1, 1024, 0, stream>>>(bsum, nb);
    scan_local_k<<<nb, 1024, 0, stream>>>(counts, bsum, offsets, cursor, dinv, n);
    scatter_k<<<(E + B - 1) / B, B, 0, stream>>>(src, dst, cursor, srcs, E);

    // ---- network ----
    const int gemm_grid = (n + 63) / 64;
    mfma_gemm_k<LOOKBACK, true, true, false><<<gemm_grid, 256, 0, stream>>>(
        x, WinT, b_in, nullptr, bufA, n);

    const int agg_grid = (n * 64 + 255) / 256;
    for (int l = 0; l < NLAYERS; ++l) {
        mfma_gemm_k<HID, false, false, true><<<gemm_grid, 256, 0, stream>>>(
            bufA, WsT + (size_t)l * HID * HID, nullptr, dinv, bufB, n);
        agg_k<0><<<agg_grid, 256, 0, stream>>>(bufB, bufA, dinv, offsets, counts,
                                               srcs, bs + (size_t)l * HID, n);
        agg_k<64><<<agg_grid, 256, 0, stream>>>(bufB, bufA, dinv, offsets, counts,
                                                srcs, bs + (size_t)l * HID, n);
    }

    gemm_out_k<<<gemm_grid, 256, 0, stream>>>(bufA, WoutT, b_out, y,
                                              out, out + (size_t)n * HORIZON, n);
}

// Round 7
// 273.413 us; speedup vs baseline: 1.1084x; 1.1084x over previous
//
#include <hip/hip_runtime.h>
#include <hip/hip_bf16.h>

#define LOOKBACK 96
#define HID 128
#define HORIZON 24
#define NLAYERS 3

typedef __attribute__((ext_vector_type(8))) short short8v;
typedef __attribute__((ext_vector_type(4))) float f32x4;

__device__ __forceinline__ float bf_lo(uint u) { return __uint_as_float(u << 16); }
__device__ __forceinline__ float bf_hi(uint u) { return __uint_as_float(u & 0xffff0000u); }
__device__ __forceinline__ ushort f2bf(float f) {
    __hip_bfloat16 h = __float2bfloat16(f);
    return *(ushort*)&h;
}

// ---------------------------------------------------------------------------
// W_out prep: WoutT[32][128] bf16, rows 24..31 zero. 4096 indices.
// ---------------------------------------------------------------------------
__global__ void wprep_out_k(const float* __restrict__ W_out, ushort* __restrict__ WoutT) {
    int idx = blockIdx.x * 256 + threadIdx.x;
    if (idx < 3072) {                        // W_out [128][24]
        int k = idx / 24, c = idx % 24;
        WoutT[c * 128 + k] = f2bf(W_out[idx]);
    } else if (idx < 4096) {
        WoutT[3072 + (idx - 3072)] = 0;      // rows 24..31
    }
}

// ---------------------------------------------------------------------------
// CSR build (counts zeroed via hipMemsetAsync)
// ---------------------------------------------------------------------------
__global__ void hist_k(const int* __restrict__ dst, int* __restrict__ counts, int E) {
    int e = blockIdx.x * blockDim.x + threadIdx.x;
    if (e < E) atomicAdd(&counts[dst[e]], 1);
}

// per-block (1024 nodes) sum of PADDED counts
__global__ __launch_bounds__(1024) void bsum_k(const int* __restrict__ counts,
                                               int* __restrict__ bsum, int n) {
    __shared__ int s[1024];
    int t = threadIdx.x;
    int i = blockIdx.x * 1024 + t;
    s[t] = (i < n) ? ((counts[i] + 7) & ~7) : 0;
    __syncthreads();
    for (int off = 512; off > 0; off >>= 1) {
        if (t < off) s[t] += s[t + off];
        __syncthreads();
    }
    if (t == 0) bsum[blockIdx.x] = s[0];
}

__global__ __launch_bounds__(1024) void scan_bsum_k(int* __restrict__ bsum, int nb) {
    __shared__ int s[1024];
    int t = threadIdx.x;
    int orig = (t < nb) ? bsum[t] : 0;
    s[t] = orig;
    __syncthreads();
    for (int off = 1; off < 1024; off <<= 1) {
        int x = s[t];
        int y = (t >= off) ? s[t - off] : 0;
        __syncthreads();
        s[t] = x + y;
        __syncthreads();
    }
    if (t < nb) bsum[t] = s[t] - orig;   // exclusive
}

// local scan of padded counts + block offset -> offsets, cursor; dinv from real count
__global__ __launch_bounds__(1024) void scan_local_k(const int* __restrict__ counts,
                                                     const int* __restrict__ bsum,
                                                     int* __restrict__ offsets,
                                                     int* __restrict__ cursor,
                                                     float* __restrict__ dinv, int n) {
    __shared__ int s[1024];
    int t = threadIdx.x;
    int i = blockIdx.x * 1024 + t;
    int c = (i < n) ? counts[i] : 0;
    int pc = (c + 7) & ~7;
    s[t] = pc;
    __syncthreads();
    for (int off = 1; off < 1024; off <<= 1) {
        int x = s[t];
        int y = (t >= off) ? s[t - off] : 0;
        __syncthreads();
        s[t] = x + y;
        __syncthreads();
    }
    if (i < n) {
        int o = bsum[blockIdx.x] + s[t] - pc;
        offsets[i] = o;
        cursor[i] = o;
        dinv[i] = rsqrtf((float)c + 1.0f);
    }
}

// fill pad slots [off+cnt, off+pc) with dummy src = n (zero row)
__global__ void pad_fill_k(const int* __restrict__ counts, const int* __restrict__ offsets,
                           int* __restrict__ srcs, int n) {
    int i = blockIdx.x * 256 + threadIdx.x;
    if (i >= n) return;
    int c = counts[i];
    int pc = (c + 7) & ~7;
    int off = offsets[i];
    for (int j = c; j < pc; ++j) srcs[off + j] = n;
}

__global__ void scatter_k(const int* __restrict__ src, const int* __restrict__ dst,
                          int* __restrict__ cursor, int* __restrict__ srcs, int E) {
    int e = blockIdx.x * blockDim.x + threadIdx.x;
    if (e >= E) return;
    int pos = atomicAdd(&cursor[dst[e]], 1);
    srcs[pos] = src[e];
}

// ---------------------------------------------------------------------------
// fused aggregation (bf16 in/out, fp32 accumulate), zh pre-scaled by dinv.
// Padded edge lists (multiple of 8; pads point at zero row n).
// out[i] = relu( dinv[i]*( zh[i] + Sum_e zh[src] ) + bias )
// one wave per node, 2 features per lane.
// ---------------------------------------------------------------------------
__global__ __launch_bounds__(256) void agg_k(
    const ushort* __restrict__ zh, ushort* __restrict__ out,
    const float* __restrict__ dinv,
    const int* __restrict__ offsets, const int* __restrict__ counts,
    const int* __restrict__ srcs,
    const float* __restrict__ bias, int n)
{
    int node = (blockIdx.x * 256 + threadIdx.x) >> 6;
    if (node >= n) return;
    node = __builtin_amdgcn_readfirstlane(node);   // wave-uniform -> scalar loads
    int lane = threadIdx.x & 63;
    int c = lane * 2;

    float di = dinv[node];
    uint sv = *(const uint*)&zh[(size_t)node * HID + c];
    float s0 = bf_lo(sv), s1 = bf_hi(sv);

    int pc = (counts[node] + 7) & ~7;
    const int* ep = srcs + offsets[node];
    for (int i = 0; i < pc; i += 8) {
        uint u0 = *(const uint*)&zh[(size_t)ep[i + 0] * HID + c];
        uint u1 = *(const uint*)&zh[(size_t)ep[i + 1] * HID + c];
        uint u2 = *(const uint*)&zh[(size_t)ep[i + 2] * HID + c];
        uint u3 = *(const uint*)&zh[(size_t)ep[i + 3] * HID + c];
        uint u4 = *(const uint*)&zh[(size_t)ep[i + 4] * HID + c];
        uint u5 = *(const uint*)&zh[(size_t)ep[i + 5] * HID + c];
        uint u6 = *(const uint*)&zh[(size_t)ep[i + 6] * HID + c];
        uint u7 = *(const uint*)&zh[(size_t)ep[i + 7] * HID + c];
        s0 += bf_lo(u0) + bf_lo(u1) + bf_lo(u2) + bf_lo(u3)
            + bf_lo(u4) + bf_lo(u5) + bf_lo(u6) + bf_lo(u7);
        s1 += bf_hi(u0) + bf_hi(u1) + bf_hi(u2) + bf_hi(u3)
            + bf_hi(u4) + bf_hi(u5) + bf_hi(u6) + bf_hi(u7);
    }

    float2 bv = *(const float2*)&bias[c];
    float r0 = fmaxf(fmaf(di, s0, bv.x), 0.0f);
    float r1 = fmaxf(fmaf(di, s1, bv.y), 0.0f);
    uint pk = (uint)f2bf(r0) | ((uint)f2bf(r1) << 16);
    *(uint*)&out[(size_t)node * HID + c] = pk;
}

// ---------------------------------------------------------------------------
// MFMA GEMM: C_bf16[n][128] = op( A[n][K] @ B_f32[K][128] )
//   AF32: A is f32 (convert in-kernel); BIAS: +bias[col]; SCALE: *dinv[row]
// block: 256 threads = 4 waves; tile 64 rows x 128 cols
// B staged transposed bf16 in LDS (stride 136 -> 2-way/free bank pattern)
// ---------------------------------------------------------------------------
template <int K, bool AF32, bool BIAS, bool SCALE>
__global__ __launch_bounds__(256) void mfma_gemm_k(
    const void* __restrict__ Araw, const float* __restrict__ B,
    const float* __restrict__ bias, const float* __restrict__ dinv,
    ushort* __restrict__ C, int n)
{
    constexpr int KSTEPS = K / 32;
    __shared__ ushort Bt[128][136];

    const int tid = threadIdx.x;
    const int wid = tid >> 6;
    const int lane = tid & 63;
    const int brow = blockIdx.x * 64;

    // stage B transposed (f32 -> bf16): Bt[col][k] = B[k][col], float4 loads
    #pragma unroll
    for (int i = tid; i < K * 32; i += 256) {
        float4 v = ((const float4*)B)[i];
        int idx = 4 * i;
        int k = idx >> 7;
        int cc = idx & 127;
        Bt[cc][k] = f2bf(v.x);
        Bt[cc + 1][k] = f2bf(v.y);
        Bt[cc + 2][k] = f2bf(v.z);
        Bt[cc + 3][k] = f2bf(v.w);
    }
    __syncthreads();

    // A fragment: row = l&15 (+wave offset), k-chunk = (l>>4)*8
    const int arow = brow + wid * 16 + (lane & 15);
    const int rowc = (arow < n) ? arow : (n - 1);
    const int kb = (lane >> 4) * 8;

    f32x4 acc[8];
    #pragma unroll
    for (int j = 0; j < 8; ++j) acc[j] = (f32x4){0.f, 0.f, 0.f, 0.f};

    #pragma unroll
    for (int kt = 0; kt < KSTEPS; ++kt) {
        short8v a;
        if (AF32) {
            const float* ap = (const float*)Araw + (size_t)rowc * K + kt * 32 + kb;
            float4 f0 = *(const float4*)ap;
            float4 f1 = *(const float4*)(ap + 4);
            a[0] = (short)f2bf(f0.x); a[1] = (short)f2bf(f0.y);
            a[2] = (short)f2bf(f0.z); a[3] = (short)f2bf(f0.w);
            a[4] = (short)f2bf(f1.x); a[5] = (short)f2bf(f1.y);
            a[6] = (short)f2bf(f1.z); a[7] = (short)f2bf(f1.w);
        } else {
            a = *(const short8v*)((const ushort*)Araw + (size_t)rowc * K + kt * 32 + kb);
        }
        #pragma unroll
        for (int j = 0; j < 8; ++j) {
            short8v b = *(const short8v*)&Bt[j * 16 + (lane & 15)][kt * 32 + kb];
            acc[j] = __builtin_amdgcn_mfma_f32_16x16x32_bf16(a, b, acc[j], 0, 0, 0);
        }
    }

    // epilogue: C/D layout col = lane&15 (+16j), row = (lane>>4)*4 + r
    const int r0 = brow + wid * 16 + (lane >> 4) * 4;
    const int cl = lane & 15;
    float dsc[4];
    if (SCALE) {
        #pragma unroll
        for (int r = 0; r < 4; ++r) dsc[r] = (r0 + r < n) ? dinv[r0 + r] : 0.0f;
    }
    #pragma unroll
    for (int j = 0; j < 8; ++j) {
        int col = j * 16 + cl;
        float bv = BIAS ? bias[col] : 0.0f;
        #pragma unroll
        for (int r = 0; r < 4; ++r) {
            int row = r0 + r;
            if (row < n) {
                float v = acc[j][r];
                if (SCALE) v *= dsc[r];
                if (BIAS) v += bv;
                C[(size_t)row * HID + col] = f2bf(v);
            }
        }
    }
}

// ---------------------------------------------------------------------------
// output MFMA GEMM: out_f32[n][24] = A_bf16[n][128] @ WoutT^T + b ; fuses y copy
// WoutT bf16 [32][128] (rows 24..31 zero). tile 64 rows x 32 cols.
// ---------------------------------------------------------------------------
__global__ __launch_bounds__(256) void gemm_out_k(
    const ushort* __restrict__ A, const ushort* __restrict__ BT,
    const float* __restrict__ bias, const float* __restrict__ y,
    float* __restrict__ out, float* __restrict__ ycopy, int n)
{
    const int tid = threadIdx.x;
    const int wid = tid >> 6;
    const int lane = tid & 63;
    const int brow = blockIdx.x * 64;
    const int arow = brow + wid * 16 + (lane & 15);
    const int rowc = (arow < n) ? arow : (n - 1);
    const int kb = (lane >> 4) * 8;

    f32x4 acc[2];
    acc[0] = (f32x4){0.f, 0.f, 0.f, 0.f};
    acc[1] = (f32x4){0.f, 0.f, 0.f, 0.f};

    #pragma unroll
    for (int kt = 0; kt < 4; ++kt) {
        short8v a = *(const short8v*)(A + (size_t)rowc * HID + kt * 32 + kb);
        #pragma unroll
        for (int j = 0; j < 2; ++j) {
            short8v b = *(const short8v*)&BT[(size_t)(j * 16 + (lane & 15)) * HID + kt * 32 + kb];
            acc[j] = __builtin_amdgcn_mfma_f32_16x16x32_bf16(a, b, acc[j], 0, 0, 0);
        }
    }

    const int r0 = brow + wid * 16 + (lane >> 4) * 4;
    const int cl = lane & 15;
    #pragma unroll
    for (int j = 0; j < 2; ++j) {
        int col = j * 16 + cl;
        if (col < HORIZON) {
            float bv = bias[col];
            #pragma unroll
            for (int r = 0; r < 4; ++r) {
                int row = r0 + r;
                if (row < n) out[(size_t)row * HORIZON + col] = acc[j][r] + bv;
            }
        }
    }

    // fused y copy: this block's 64 rows = 384 float4s
    const float4* y4 = (const float4*)y;
    float4* o4 = (float4*)ycopy;
    const int lim = n * 6;          // n*24/4
    int base = blockIdx.x * 384;
    for (int t = tid; t < 384; t += 256) {
        int i = base + t;
        if (i < lim) o4[i] = y4[i];
    }
}

// ---------------------------------------------------------------------------
extern "C" void kernel_launch(void* const* d_in, const int* in_sizes, int n_in,
                              void* d_out, int out_size, void* d_ws, size_t ws_size,
                              hipStream_t stream) {
    const float* x     = (const float*)d_in[0];
    const float* y     = (const float*)d_in[1];
    const int*   ei    = (const int*)d_in[2];     // int64 in ref -> int32 on device
    const float* W_in  = (const float*)d_in[3];
    const float* b_in  = (const float*)d_in[4];
    const float* Ws    = (const float*)d_in[5];
    const float* bs    = (const float*)d_in[6];
    const float* W_out = (const float*)d_in[7];
    const float* b_out = (const float*)d_in[8];
    float* out = (float*)d_out;

    const int n = in_sizes[0] / LOOKBACK;
    const int E = in_sizes[2] / 2;
    const int* src = ei;
    const int* dst = ei + E;
    const int nb = (n + 1023) / 1024;

    // workspace layout
    char* p = (char*)d_ws;
    float*  dinv    = (float*)p;   p += (size_t)n * 4;
    int*    counts  = (int*)p;     p += (size_t)n * 4;
    int*    offsets = (int*)p;     p += (size_t)n * 4;
    int*    cursor  = (int*)p;     p += (size_t)n * 4;
    int*    bsum    = (int*)p;     p += (size_t)1024 * 4;
    int*    srcs    = (int*)p;     p += (size_t)(E + 8 * n) * 4;   // padded CSR
    ushort* WoutT   = (ushort*)p;  p += (size_t)32 * 128 * 2;
    ushort* bufA    = (ushort*)p;  p += (size_t)(n + 1) * HID * 2;
    ushort* bufB    = (ushort*)p;  p += (size_t)(n + 1) * HID * 2;

    const int B = 256;
    // ---- prep + CSR build ----
    wprep_out_k<<<16, 256, 0, stream>>>(W_out, WoutT);
    hipMemsetAsync(counts, 0, (size_t)n * 4, stream);
    hipMemsetAsync(bufB + (size_t)n * HID, 0, HID * 2, stream);   // zero row for pads
    hist_k<<<(E + B - 1) / B, B, 0, stream>>>(dst, counts, E);
    bsum_k<<<nb, 1024, 0, stream>>>(counts, bsum, n);
    scan_bsum_k<<<1, 1024, 0, stream>>>(bsum, nb);
    scan_local_k<<<nb, 1024, 0, stream>>>(counts, bsum, offsets, cursor, dinv, n);
    pad_fill_k<<<(n + B - 1) / B, B, 0, stream>>>(counts, offsets, srcs, n);
    scatter_k<<<(E + B - 1) / B, B, 0, stream>>>(src, dst, cursor, srcs, E);

    // ---- network ----
    const int gemm_grid = (n + 63) / 64;
    mfma_gemm_k<LOOKBACK, true, true, false><<<gemm_grid, 256, 0, stream>>>(
        x, W_in, b_in, nullptr, bufA, n);

    const int agg_grid = (n * 64 + 255) / 256;
    for (int l = 0; l < NLAYERS; ++l) {
        mfma_gemm_k<HID, false, false, true><<<gemm_grid, 256, 0, stream>>>(
            bufA, Ws + (size_t)l * HID * HID, nullptr, dinv, bufB, n);
        agg_k<<<agg_grid, 256, 0, stream>>>(bufB, bufA, dinv, offsets, counts,
                                            srcs, bs + (size_t)l * HID, n);
    }

    gemm_out_k<<<gemm_grid, 256, 0, stream>>>(bufA, WoutT, b_out, y,
                                              out, out + (size_t)n * HORIZON, n);
}

// Round 8
// 260.146 us; speedup vs baseline: 1.1649x; 1.0510x over previous
//
#include <hip/hip_runtime.h>
#include <hip/hip_bf16.h>

#define LOOKBACK 96
#define HID 128
#define HORIZON 24
#define NLAYERS 3

typedef __attribute__((ext_vector_type(8))) short short8v;
typedef __attribute__((ext_vector_type(4))) float f32x4;

__device__ __forceinline__ float bf_lo(uint u) { return __uint_as_float(u << 16); }
__device__ __forceinline__ float bf_hi(uint u) { return __uint_as_float(u & 0xffff0000u); }
__device__ __forceinline__ ushort f2bf(float f) {
    __hip_bfloat16 h = __float2bfloat16(f);
    return *(ushort*)&h;
}

// ---------------------------------------------------------------------------
// CSR build (counts zeroed via hipMemsetAsync). Pad granularity 16.
// ---------------------------------------------------------------------------
__global__ void hist_k(const int* __restrict__ dst, int* __restrict__ counts, int E) {
    int e = blockIdx.x * blockDim.x + threadIdx.x;
    if (e < E) atomicAdd(&counts[dst[e]], 1);
}

// per-block (1024 nodes) sum of PADDED counts
__global__ __launch_bounds__(1024) void bsum_k(const int* __restrict__ counts,
                                               int* __restrict__ bsum, int n) {
    __shared__ int s[1024];
    int t = threadIdx.x;
    int i = blockIdx.x * 1024 + t;
    s[t] = (i < n) ? ((counts[i] + 15) & ~15) : 0;
    __syncthreads();
    for (int off = 512; off > 0; off >>= 1) {
        if (t < off) s[t] += s[t + off];
        __syncthreads();
    }
    if (t == 0) bsum[blockIdx.x] = s[0];
}

__global__ __launch_bounds__(1024) void scan_bsum_k(int* __restrict__ bsum, int nb) {
    __shared__ int s[1024];
    int t = threadIdx.x;
    int orig = (t < nb) ? bsum[t] : 0;
    s[t] = orig;
    __syncthreads();
    for (int off = 1; off < 1024; off <<= 1) {
        int x = s[t];
        int y = (t >= off) ? s[t - off] : 0;
        __syncthreads();
        s[t] = x + y;
        __syncthreads();
    }
    if (t < nb) bsum[t] = s[t] - orig;   // exclusive
}

// local scan of padded counts + block offset -> offsets, cursor; dinv from real count
__global__ __launch_bounds__(1024) void scan_local_k(const int* __restrict__ counts,
                                                     const int* __restrict__ bsum,
                                                     int* __restrict__ offsets,
                                                     int* __restrict__ cursor,
                                                     float* __restrict__ dinv, int n) {
    __shared__ int s[1024];
    int t = threadIdx.x;
    int i = blockIdx.x * 1024 + t;
    int c = (i < n) ? counts[i] : 0;
    int pc = (c + 15) & ~15;
    s[t] = pc;
    __syncthreads();
    for (int off = 1; off < 1024; off <<= 1) {
        int x = s[t];
        int y = (t >= off) ? s[t - off] : 0;
        __syncthreads();
        s[t] = x + y;
        __syncthreads();
    }
    if (i < n) {
        int o = bsum[blockIdx.x] + s[t] - pc;
        offsets[i] = o;
        cursor[i] = o;
        dinv[i] = rsqrtf((float)c + 1.0f);
    }
}

// fill pad slots with dummy src = n (zero row); also prep WoutT and zero row
__global__ void pad_fill_k(const int* __restrict__ counts, const int* __restrict__ offsets,
                           int* __restrict__ srcs,
                           const float* __restrict__ W_out, ushort* __restrict__ WoutT,
                           ushort* __restrict__ zrow, int n) {
    int i = blockIdx.x * 256 + threadIdx.x;
    if (i < 3072) {                          // W_out [128][24] -> WoutT [32][128]
        int k = i / 24, cc = i % 24;
        WoutT[cc * 128 + k] = f2bf(W_out[i]);
    } else if (i < 4096) {
        WoutT[i] = 0;                        // rows 24..31
    }
    if (i < 64) ((uint*)zrow)[i] = 0;        // zero feature row for pad gathers
    if (i >= n) return;
    int c = counts[i];
    int pc = (c + 15) & ~15;
    int off = offsets[i];
    for (int j = c; j < pc; ++j) srcs[off + j] = n;
}

__global__ void scatter_k(const int* __restrict__ src, const int* __restrict__ dst,
                          int* __restrict__ cursor, int* __restrict__ srcs, int E) {
    int e = blockIdx.x * blockDim.x + threadIdx.x;
    if (e >= E) return;
    int pos = atomicAdd(&cursor[dst[e]], 1);
    srcs[pos] = src[e];
}

// ---------------------------------------------------------------------------
// fused aggregation (bf16 in/out, fp32 accumulate), zh pre-scaled by dinv.
// Edge lists padded to multiple of 16 (pads -> zero row n).
// out[i] = relu( dinv[i]*( zh[i] + Sum_e zh[src] ) + bias )
// one wave per node, 2 features per lane; 16 dependence-free gathers per batch.
// ---------------------------------------------------------------------------
__global__ __launch_bounds__(256) void agg_k(
    const ushort* __restrict__ zh, ushort* __restrict__ out,
    const float* __restrict__ dinv,
    const int* __restrict__ offsets, const int* __restrict__ counts,
    const int* __restrict__ srcs,
    const float* __restrict__ bias, int n)
{
    int node = (blockIdx.x * 256 + threadIdx.x) >> 6;
    if (node >= n) return;
    node = __builtin_amdgcn_readfirstlane(node);   // wave-uniform -> scalar loads
    int lane = threadIdx.x & 63;
    int c = lane * 2;

    float di = dinv[node];
    uint sv = *(const uint*)&zh[(size_t)node * HID + c];
    float s0 = bf_lo(sv), s1 = bf_hi(sv);

    int pc = (counts[node] + 15) & ~15;
    const int* ep = srcs + offsets[node];
    for (int i = 0; i < pc; i += 16) {
        uint u[16];
        #pragma unroll
        for (int j = 0; j < 16; ++j)
            u[j] = *(const uint*)&zh[(size_t)ep[i + j] * HID + c];
        #pragma unroll
        for (int j = 0; j < 16; ++j) {
            s0 += bf_lo(u[j]);
            s1 += bf_hi(u[j]);
        }
    }

    float2 bv = *(const float2*)&bias[c];
    float r0 = fmaxf(fmaf(di, s0, bv.x), 0.0f);
    float r1 = fmaxf(fmaf(di, s1, bv.y), 0.0f);
    uint pk = (uint)f2bf(r0) | ((uint)f2bf(r1) << 16);
    *(uint*)&out[(size_t)node * HID + c] = pk;
}

// ---------------------------------------------------------------------------
// MFMA GEMM: C_bf16[n][128] = op( A[n][K] @ B_f32[K][128] )
//   AF32: A is f32 (convert in-kernel); BIAS: +bias[col]; SCALE: *dinv[row]
// block: 256 threads = 4 waves; tile 64 rows x 128 cols
// B staged transposed bf16 in LDS; C staged via LDS for coalesced b128 stores
// ---------------------------------------------------------------------------
template <int K, bool AF32, bool BIAS, bool SCALE>
__global__ __launch_bounds__(256) void mfma_gemm_k(
    const void* __restrict__ Araw, const float* __restrict__ B,
    const float* __restrict__ bias, const float* __restrict__ dinv,
    ushort* __restrict__ C, int n)
{
    constexpr int KSTEPS = K / 32;
    __shared__ ushort Bt[128][136];   // B^T; reused as C-stage after MFMA

    const int tid = threadIdx.x;
    const int wid = tid >> 6;
    const int lane = tid & 63;
    const int brow = blockIdx.x * 64;

    // stage B transposed (f32 -> bf16): Bt[col][k] = B[k][col], float4 loads
    #pragma unroll
    for (int i = tid; i < K * 32; i += 256) {
        float4 v = ((const float4*)B)[i];
        int idx = 4 * i;
        int k = idx >> 7;
        int cc = idx & 127;
        Bt[cc][k] = f2bf(v.x);
        Bt[cc + 1][k] = f2bf(v.y);
        Bt[cc + 2][k] = f2bf(v.z);
        Bt[cc + 3][k] = f2bf(v.w);
    }
    __syncthreads();

    // A fragment: row = l&15 (+wave offset), k-chunk = (l>>4)*8
    const int arow = brow + wid * 16 + (lane & 15);
    const int rowc = (arow < n) ? arow : (n - 1);
    const int kb = (lane >> 4) * 8;

    f32x4 acc[8];
    #pragma unroll
    for (int j = 0; j < 8; ++j) acc[j] = (f32x4){0.f, 0.f, 0.f, 0.f};

    #pragma unroll
    for (int kt = 0; kt < KSTEPS; ++kt) {
        short8v a;
        if (AF32) {
            const float* ap = (const float*)Araw + (size_t)rowc * K + kt * 32 + kb;
            float4 f0 = *(const float4*)ap;
            float4 f1 = *(const float4*)(ap + 4);
            a[0] = (short)f2bf(f0.x); a[1] = (short)f2bf(f0.y);
            a[2] = (short)f2bf(f0.z); a[3] = (short)f2bf(f0.w);
            a[4] = (short)f2bf(f1.x); a[5] = (short)f2bf(f1.y);
            a[6] = (short)f2bf(f1.z); a[7] = (short)f2bf(f1.w);
        } else {
            a = *(const short8v*)((const ushort*)Araw + (size_t)rowc * K + kt * 32 + kb);
        }
        #pragma unroll
        for (int j = 0; j < 8; ++j) {
            short8v b = *(const short8v*)&Bt[j * 16 + (lane & 15)][kt * 32 + kb];
            acc[j] = __builtin_amdgcn_mfma_f32_16x16x32_bf16(a, b, acc[j], 0, 0, 0);
        }
    }

    // epilogue: stage C tile in LDS (reuse Bt), then coalesced b128 stores.
    // C/D frag layout: col = lane&15 (+16j), local row = wid*16 + (lane>>4)*4 + r
    const int r0l = wid * 16 + (lane >> 4) * 4;
    float dsc[4];
    if (SCALE) {
        #pragma unroll
        for (int r = 0; r < 4; ++r)
            dsc[r] = (brow + r0l + r < n) ? dinv[brow + r0l + r] : 0.0f;
    }
    __syncthreads();                      // all Bt reads complete
    ushort* Cs = &Bt[0][0];               // [64][136] view
    const int cl = lane & 15;
    #pragma unroll
    for (int j = 0; j < 8; ++j) {
        int col = j * 16 + cl;
        float bv = BIAS ? bias[col] : 0.0f;
        #pragma unroll
        for (int r = 0; r < 4; ++r) {
            float v = acc[j][r];
            if (SCALE) v *= dsc[r];
            if (BIAS) v += bv;
            Cs[(r0l + r) * 136 + col] = f2bf(v);
        }
    }
    __syncthreads();
    int lrow = tid >> 2;
    int seg = (tid & 3) * 32;
    int grow = brow + lrow;
    if (grow < n) {
        #pragma unroll
        for (int q = 0; q < 4; ++q) {
            short8v v = *(const short8v*)&Cs[lrow * 136 + seg + q * 8];
            *(short8v*)&C[(size_t)grow * HID + seg + q * 8] = v;
        }
    }
}

// ---------------------------------------------------------------------------
// output MFMA GEMM: out_f32[n][24] = A_bf16[n][128] @ WoutT^T + b ; fuses y copy
// WoutT bf16 [32][128] (rows 24..31 zero). tile 64 rows x 32 cols.
// ---------------------------------------------------------------------------
__global__ __launch_bounds__(256) void gemm_out_k(
    const ushort* __restrict__ A, const ushort* __restrict__ BT,
    const float* __restrict__ bias, const float* __restrict__ y,
    float* __restrict__ out, float* __restrict__ ycopy, int n)
{
    const int tid = threadIdx.x;
    const int wid = tid >> 6;
    const int lane = tid & 63;
    const int brow = blockIdx.x * 64;
    const int arow = brow + wid * 16 + (lane & 15);
    const int rowc = (arow < n) ? arow : (n - 1);
    const int kb = (lane >> 4) * 8;

    f32x4 acc[2];
    acc[0] = (f32x4){0.f, 0.f, 0.f, 0.f};
    acc[1] = (f32x4){0.f, 0.f, 0.f, 0.f};

    #pragma unroll
    for (int kt = 0; kt < 4; ++kt) {
        short8v a = *(const short8v*)(A + (size_t)rowc * HID + kt * 32 + kb);
        #pragma unroll
        for (int j = 0; j < 2; ++j) {
            short8v b = *(const short8v*)&BT[(size_t)(j * 16 + (lane & 15)) * HID + kt * 32 + kb];
            acc[j] = __builtin_amdgcn_mfma_f32_16x16x32_bf16(a, b, acc[j], 0, 0, 0);
        }
    }

    const int r0 = brow + wid * 16 + (lane >> 4) * 4;
    const int cl = lane & 15;
    #pragma unroll
    for (int j = 0; j < 2; ++j) {
        int col = j * 16 + cl;
        if (col < HORIZON) {
            float bv = bias[col];
            #pragma unroll
            for (int r = 0; r < 4; ++r) {
                int row = r0 + r;
                if (row < n) out[(size_t)row * HORIZON + col] = acc[j][r] + bv;
            }
        }
    }

    // fused y copy: this block's 64 rows = 384 float4s
    const float4* y4 = (const float4*)y;
    float4* o4 = (float4*)ycopy;
    const int lim = n * 6;          // n*24/4
    int base = blockIdx.x * 384;
    for (int t = tid; t < 384; t += 256) {
        int i = base + t;
        if (i < lim) o4[i] = y4[i];
    }
}

// ---------------------------------------------------------------------------
extern "C" void kernel_launch(void* const* d_in, const int* in_sizes, int n_in,
                              void* d_out, int out_size, void* d_ws, size_t ws_size,
                              hipStream_t stream) {
    const float* x     = (const float*)d_in[0];
    const float* y     = (const float*)d_in[1];
    const int*   ei    = (const int*)d_in[2];     // int64 in ref -> int32 on device
    const float* W_in  = (const float*)d_in[3];
    const float* b_in  = (const float*)d_in[4];
    const float* Ws    = (const float*)d_in[5];
    const float* bs    = (const float*)d_in[6];
    const float* W_out = (const float*)d_in[7];
    const float* b_out = (const float*)d_in[8];
    float* out = (float*)d_out;

    const int n = in_sizes[0] / LOOKBACK;
    const int E = in_sizes[2] / 2;
    const int* src = ei;
    const int* dst = ei + E;
    const int nb = (n + 1023) / 1024;

    // workspace layout
    char* p = (char*)d_ws;
    float*  dinv    = (float*)p;   p += (size_t)n * 4;
    int*    counts  = (int*)p;     p += (size_t)n * 4;
    int*    offsets = (int*)p;     p += (size_t)n * 4;
    int*    cursor  = (int*)p;     p += (size_t)n * 4;
    int*    bsum    = (int*)p;     p += (size_t)1024 * 4;
    int*    srcs    = (int*)p;     p += (size_t)(E + 16 * (size_t)n) * 4;   // padded CSR
    ushort* WoutT   = (ushort*)p;  p += (size_t)32 * 128 * 2;
    ushort* bufA    = (ushort*)p;  p += (size_t)(n + 1) * HID * 2;
    ushort* bufB    = (ushort*)p;  p += (size_t)(n + 1) * HID * 2;

    const int B = 256;
    // ---- CSR build + prep ----
    hipMemsetAsync(counts, 0, (size_t)n * 4, stream);
    hist_k<<<(E + B - 1) / B, B, 0, stream>>>(dst, counts, E);
    bsum_k<<<nb, 1024, 0, stream>>>(counts, bsum, n);
    scan_bsum_k<<<1, 1024, 0, stream>>>(bsum, nb);
    scan_local_k<<<nb, 1024, 0, stream>>>(counts, bsum, offsets, cursor, dinv, n);
    pad_fill_k<<<(n + B - 1) / B, B, 0, stream>>>(counts, offsets, srcs,
                                                  W_out, WoutT, bufB + (size_t)n * HID, n);
    scatter_k<<<(E + B - 1) / B, B, 0, stream>>>(src, dst, cursor, srcs, E);

    // ---- network ----
    const int gemm_grid = (n + 63) / 64;
    mfma_gemm_k<LOOKBACK, true, true, false><<<gemm_grid, 256, 0, stream>>>(
        x, W_in, b_in, nullptr, bufA, n);

    const int agg_grid = (n * 64 + 255) / 256;
    for (int l = 0; l < NLAYERS; ++l) {
        mfma_gemm_k<HID, false, false, true><<<gemm_grid, 256, 0, stream>>>(
            bufA, Ws + (size_t)l * HID * HID, nullptr, dinv, bufB, n);
        agg_k<<<agg_grid, 256, 0, stream>>>(bufB, bufA, dinv, offsets, counts,
                                            srcs, bs + (size_t)l * HID, n);
    }

    gemm_out_k<<<gemm_grid, 256, 0, stream>>>(bufA, WoutT, b_out, y,
                                              out, out + (size_t)n * HORIZON, n);
}